// Round 1
// baseline (3041.191 us; speedup 1.0000x reference)
//
#include <hip/hip_runtime.h>

#define D 64
#define BATCH 4

// --- Phase 1: xw[b,n,:] = x[b,n,:] @ W  (dense [B*N,64] @ [64,64]) ---
// Block = 256 threads = 4 nodes x 64 channels; 16 nodes per block (4 groups).
__global__ __launch_bounds__(256) void gemm_xw_kernel(
    const float* __restrict__ x, const float* __restrict__ W,
    float* __restrict__ xw, int total_nodes) {
  __shared__ float Ws[D][D];   // W staged once per block
  __shared__ float xs[4][D];   // 4 x-rows per group

  const int tid = threadIdx.x;
  for (int i = tid; i < D * D; i += 256) Ws[i / D][i % D] = W[i];

  const int c  = tid & 63;   // output channel
  const int ln = tid >> 6;   // node-within-group 0..3
  const int base = blockIdx.x * 16;

  for (int g = 0; g < 4; ++g) {
    const int node = base + g * 4 + ln;
    __syncthreads();  // protects xs from prev group; covers Ws on g=0
    xs[ln][c] = (node < total_nodes) ? x[(size_t)node * D + c] : 0.f;
    __syncthreads();
    if (node < total_nodes) {
      float acc = 0.f;
#pragma unroll
      for (int k = 0; k < D; ++k) acc += xs[ln][k] * Ws[k][c];
      xw[(size_t)node * D + c] = acc;
    }
  }
}

// --- Phase 2: out[b, rows[e], :] += a_vals[e] * xw[b, cols[e], :] ---
// Thread t: edge = t/16, quad = t%16 -> float4 of channels. Wave = 4 edges.
__global__ __launch_bounds__(256) void scatter_kernel(
    const float* __restrict__ xw, const int* __restrict__ rows,
    const int* __restrict__ cols, const float* __restrict__ a_vals,
    float* __restrict__ out, int E, int stride_b /* N*D */) {
  const int t = blockIdx.x * blockDim.x + threadIdx.x;
  const int e = t >> 4;
  if (e >= E) return;
  const int q = (t & 15) << 2;  // channel offset 0,4,...,60

  const int   r  = rows[e];
  const int   c  = cols[e];
  const float av = a_vals[e];

#pragma unroll
  for (int b = 0; b < BATCH; ++b) {
    const float4 v =
        *(const float4*)(xw + (size_t)b * stride_b + (size_t)c * D + q);
    float* dst = out + (size_t)b * stride_b + (size_t)r * D + q;
    atomicAdd(dst + 0, av * v.x);
    atomicAdd(dst + 1, av * v.y);
    atomicAdd(dst + 2, av * v.z);
    atomicAdd(dst + 3, av * v.w);
  }
}

extern "C" void kernel_launch(void* const* d_in, const int* in_sizes, int n_in,
                              void* d_out, int out_size, void* d_ws,
                              size_t ws_size, hipStream_t stream) {
  const float* x      = (const float*)d_in[0];  // [B, N, D]
  const float* W      = (const float*)d_in[1];  // [D, D]
  const int*   rows   = (const int*)d_in[2];    // [E]
  const int*   cols   = (const int*)d_in[3];    // [E]
  const float* a_vals = (const float*)d_in[4];  // [E]

  const int E           = in_sizes[2];
  const int total_nodes = in_sizes[0] / D;        // B*N
  const int N           = total_nodes / BATCH;
  const int stride_b    = N * D;

  float* xw = (float*)d_ws;  // B*N*D floats = 51.2 MB

  // out accumulates via atomics -> must start at zero (harness poisons 0xAA).
  hipMemsetAsync(d_out, 0, (size_t)out_size * sizeof(float), stream);

  const int gemm_blocks = (total_nodes + 15) / 16;
  gemm_xw_kernel<<<gemm_blocks, 256, 0, stream>>>(x, W, xw, total_nodes);

  const long long sc_threads = (long long)E * 16;
  const int sc_blocks = (int)((sc_threads + 255) / 256);
  scatter_kernel<<<sc_blocks, 256, 0, stream>>>(xw, rows, cols, a_vals,
                                                (float*)d_out, E, stride_b);
}

// Round 2
// 497.409 us; speedup vs baseline: 6.1141x; 6.1141x over previous
//
#include <hip/hip_runtime.h>

#define D 64
#define BATCH 4
#define PACK (BATCH * D)  // 256 floats per node in xw_t

// --- Phase 1: xw_t[n][b][c] = sum_k x[b][n][k] * W[k][c]  (node-major packed) ---
__global__ __launch_bounds__(256) void gemm_xw_kernel(
    const float* __restrict__ x, const float* __restrict__ W,
    float* __restrict__ xw_t, int total_nodes, int N) {
  __shared__ float Ws[D][D];
  __shared__ float xs[4][D];

  const int tid = threadIdx.x;
  for (int i = tid; i < D * D; i += 256) Ws[i / D][i % D] = W[i];

  const int c  = tid & 63;
  const int ln = tid >> 6;
  const int base = blockIdx.x * 16;

  for (int g = 0; g < 4; ++g) {
    const int node = base + g * 4 + ln;  // flat index b*N + n
    __syncthreads();
    xs[ln][c] = (node < total_nodes) ? x[(size_t)node * D + c] : 0.f;
    __syncthreads();
    if (node < total_nodes) {
      float acc = 0.f;
#pragma unroll
      for (int k = 0; k < D; ++k) acc += xs[ln][k] * Ws[k][c];
      const int b = node / N;
      const int n = node - b * N;
      xw_t[(size_t)n * PACK + b * D + c] = acc;
    }
  }
}

// --- Sort step 1: degree histogram (cnt must be pre-zeroed) ---
__global__ __launch_bounds__(256) void hist_kernel(
    const int* __restrict__ rows, int* __restrict__ cnt, int E) {
  const int e = blockIdx.x * blockDim.x + threadIdx.x;
  if (e < E) atomicAdd(&cnt[rows[e]], 1);
}

// --- Sort step 2: exclusive scan of cnt -> start[0..N], cursor=start ---
// Single block, 1024 threads; cnt aliases cursor (read-before-write per elem).
__global__ __launch_bounds__(1024) void scan_kernel(
    int* __restrict__ cnt_cursor, int* __restrict__ start, int n, int E) {
  __shared__ int sums[1024];
  const int t = threadIdx.x;
  const int chunk = (n + 1023) / 1024;
  const int lo = t * chunk;
  const int hi = min(lo + chunk, n);

  int s = 0;
  for (int i = lo; i < hi; ++i) s += cnt_cursor[i];
  sums[t] = s;
  __syncthreads();
  for (int off = 1; off < 1024; off <<= 1) {
    int v = (t >= off) ? sums[t - off] : 0;
    __syncthreads();
    sums[t] += v;
    __syncthreads();
  }
  int run = (t > 0) ? sums[t - 1] : 0;  // exclusive prefix
  for (int i = lo; i < hi; ++i) {
    const int c = cnt_cursor[i];
    start[i] = run;
    cnt_cursor[i] = run;  // cursor init
    run += c;
  }
  if (t == 0) start[n] = E;
}

// --- Sort step 3: drop (col, a) into row segments ---
__global__ __launch_bounds__(256) void permute_kernel(
    const int* __restrict__ rows, const int* __restrict__ cols,
    const float* __restrict__ a_vals, int* __restrict__ cursor,
    int* __restrict__ col_s, float* __restrict__ a_s, int E) {
  const int e = blockIdx.x * blockDim.x + threadIdx.x;
  if (e >= E) return;
  const int pos = atomicAdd(&cursor[rows[e]], 1);
  col_s[pos] = cols[e];
  a_s[pos]   = a_vals[e];
}

// --- Phase 2: gather-reduce. One wave per row; lane owns float4 of packed row. ---
__global__ __launch_bounds__(256) void gather_kernel(
    const float* __restrict__ xw_t, const int* __restrict__ start,
    const int* __restrict__ col_s, const float* __restrict__ a_s,
    float* __restrict__ out, int N, int stride_b /* N*D */) {
  const int wid  = threadIdx.x >> 6;
  const int lane = threadIdx.x & 63;
  const int r = blockIdx.x * 4 + wid;
  if (r >= N) return;

  const int js = start[r];
  const int je = start[r + 1];

  float4 acc = {0.f, 0.f, 0.f, 0.f};
  for (int j = js; j < je; ++j) {
    const int   c  = col_s[j];
    const float av = a_s[j];
    const float4 v =
        *(const float4*)(xw_t + (size_t)c * PACK + lane * 4);
    acc.x += av * v.x;
    acc.y += av * v.y;
    acc.z += av * v.z;
    acc.w += av * v.w;
  }

  const int i0 = lane * 4;          // packed idx in [0,256)
  const int b  = i0 >> 6;
  const int ch = i0 & 63;
  *(float4*)(out + (size_t)b * stride_b + (size_t)r * D + ch) = acc;
}

extern "C" void kernel_launch(void* const* d_in, const int* in_sizes, int n_in,
                              void* d_out, int out_size, void* d_ws,
                              size_t ws_size, hipStream_t stream) {
  const float* x      = (const float*)d_in[0];
  const float* W      = (const float*)d_in[1];
  const int*   rows   = (const int*)d_in[2];
  const int*   cols   = (const int*)d_in[3];
  const float* a_vals = (const float*)d_in[4];

  const int E           = in_sizes[2];
  const int total_nodes = in_sizes[0] / D;  // B*N
  const int N           = total_nodes / BATCH;
  const int stride_b    = N * D;

  // Workspace layout
  char* ws = (char*)d_ws;
  float* xw_t  = (float*)ws;                        ws += (size_t)N * PACK * sizeof(float);
  int*   start = (int*)ws;                          ws += (size_t)(N + 1) * sizeof(int);
  int*   cursor= (int*)ws;                          ws += (size_t)N * sizeof(int);
  int*   col_s = (int*)ws;                          ws += (size_t)E * sizeof(int);
  float* a_s   = (float*)ws;

  hipMemsetAsync(cursor, 0, (size_t)N * sizeof(int), stream);

  const int gemm_blocks = (total_nodes + 15) / 16;
  gemm_xw_kernel<<<gemm_blocks, 256, 0, stream>>>(x, W, xw_t, total_nodes, N);

  const int eb = (E + 255) / 256;
  hist_kernel<<<eb, 256, 0, stream>>>(rows, cursor, E);
  scan_kernel<<<1, 1024, 0, stream>>>(cursor, start, N, E);
  permute_kernel<<<eb, 256, 0, stream>>>(rows, cols, a_vals, cursor, col_s, a_s, E);

  const int gb = (N + 3) / 4;
  gather_kernel<<<gb, 256, 0, stream>>>(xw_t, start, col_s, a_s,
                                        (float*)d_out, N, stride_b);
}

// Round 3
// 312.533 us; speedup vs baseline: 9.7308x; 1.5915x over previous
//
#include <hip/hip_runtime.h>
#include <hip/hip_bf16.h>

#define D 64
#define BATCH 4
#define PACK 256  // packed floats per graph node: BATCH * D

__device__ __forceinline__ float bf2f(unsigned short h) {
  union { unsigned int u; float f; } v;
  v.u = ((unsigned int)h) << 16;
  return v.f;
}

// --- Phase 1: xwb[n][b*64+c] = bf16( sum_k x[b*N+n][k] * W[k][c] ) ---
// W repacked in LDS as F[k4][c] = {W[4k4][c], W[4k4+1][c], W[4k4+2][c], W[4k4+3][c]}.
// Wave = 64 lanes = 64 channels; 4 nodes register-tiled per wave iteration.
// x loads are wave-uniform (scalar path); inner step: 1 ds_read_b128 + 16 FMA.
__global__ __launch_bounds__(256) void gemm_xw_kernel(
    const float* __restrict__ x, const float* __restrict__ W,
    __hip_bfloat16* __restrict__ xwb, int total_nodes, int N) {
  __shared__ float4 F[16][64];
  const int tid = threadIdx.x;
  for (int i = tid; i < 1024; i += 256) {
    const int k4 = i >> 6, c = i & 63;
    F[k4][c] = make_float4(W[(4 * k4 + 0) * 64 + c], W[(4 * k4 + 1) * 64 + c],
                           W[(4 * k4 + 2) * 64 + c], W[(4 * k4 + 3) * 64 + c]);
  }
  __syncthreads();

  const int lane = tid & 63;
  const int wid  = __builtin_amdgcn_readfirstlane(tid >> 6);
  const float4* __restrict__ x4 = (const float4*)x;

  for (int fn0 = blockIdx.x * 16 + wid * 4; fn0 < total_nodes;
       fn0 += gridDim.x * 16) {
    float acc0 = 0.f, acc1 = 0.f, acc2 = 0.f, acc3 = 0.f;
    if (fn0 + 4 <= total_nodes) {
#pragma unroll 4
      for (int k4 = 0; k4 < 16; ++k4) {
        const float4 wv = F[k4][lane];
        float4 xv;
        xv = x4[(size_t)(fn0 + 0) * 16 + k4];
        acc0 = fmaf(xv.x, wv.x, fmaf(xv.y, wv.y, fmaf(xv.z, wv.z, fmaf(xv.w, wv.w, acc0))));
        xv = x4[(size_t)(fn0 + 1) * 16 + k4];
        acc1 = fmaf(xv.x, wv.x, fmaf(xv.y, wv.y, fmaf(xv.z, wv.z, fmaf(xv.w, wv.w, acc1))));
        xv = x4[(size_t)(fn0 + 2) * 16 + k4];
        acc2 = fmaf(xv.x, wv.x, fmaf(xv.y, wv.y, fmaf(xv.z, wv.z, fmaf(xv.w, wv.w, acc2))));
        xv = x4[(size_t)(fn0 + 3) * 16 + k4];
        acc3 = fmaf(xv.x, wv.x, fmaf(xv.y, wv.y, fmaf(xv.z, wv.z, fmaf(xv.w, wv.w, acc3))));
      }
      float accs[4] = {acc0, acc1, acc2, acc3};
#pragma unroll
      for (int m = 0; m < 4; ++m) {
        const int fn = fn0 + m;
        const int b = fn / N;
        const int n = fn - b * N;
        xwb[(size_t)n * PACK + b * D + lane] = __float2bfloat16(accs[m]);
      }
    } else {
      for (int m = 0; m < 4; ++m) {
        const int fn = fn0 + m;
        if (fn >= total_nodes) break;
        float acc = 0.f;
        for (int k4 = 0; k4 < 16; ++k4) {
          const float4 wv = F[k4][lane];
          const float4 xv = x4[(size_t)fn * 16 + k4];
          acc = fmaf(xv.x, wv.x, fmaf(xv.y, wv.y, fmaf(xv.z, wv.z, fmaf(xv.w, wv.w, acc))));
        }
        const int b = fn / N;
        const int n = fn - b * N;
        xwb[(size_t)n * PACK + b * D + lane] = __float2bfloat16(acc);
      }
    }
  }
}

// --- Sort step 1: degree histogram into cnt (pre-zeroed) ---
__global__ __launch_bounds__(256) void hist_kernel(
    const int* __restrict__ rows, int* __restrict__ cnt, int E) {
  const int e = blockIdx.x * blockDim.x + threadIdx.x;
  if (e < E) atomicAdd(&cnt[rows[e]], 1);
}

// --- Sort step 2a: per-block exclusive scan + block totals ---
__global__ __launch_bounds__(1024) void scan_a_kernel(
    const int* __restrict__ cnt, int* __restrict__ start,
    int* __restrict__ partial, int n) {
  __shared__ int s[1024];
  const int t = threadIdx.x;
  const int i = blockIdx.x * 1024 + t;
  const int v = (i < n) ? cnt[i] : 0;
  s[t] = v;
  __syncthreads();
  for (int off = 1; off < 1024; off <<= 1) {
    const int u = (t >= off) ? s[t - off] : 0;
    __syncthreads();
    s[t] += u;
    __syncthreads();
  }
  if (i < n) start[i] = s[t] - v;  // block-local exclusive
  if (t == 1023) partial[blockIdx.x] = s[1023];
}

// --- Sort step 2b: scan block totals (one wave), set start[n]=E ---
__global__ __launch_bounds__(64) void scan_b_kernel(
    const int* __restrict__ partial, int* __restrict__ offsets,
    int* __restrict__ start, int nb, int n, int E) {
  const int lane = threadIdx.x;
  int carry = 0;
  for (int base = 0; base < nb; base += 64) {
    const int idx = base + lane;
    const int v = (idx < nb) ? partial[idx] : 0;
    int s = v;
    for (int d = 1; d < 64; d <<= 1) {
      const int u = __shfl_up(s, d);
      if (lane >= d) s += u;
    }
    if (idx < nb) offsets[idx] = carry + s - v;
    carry += __shfl(s, 63);
  }
  if (lane == 0) start[n] = E;
}

// --- Sort step 2c: add block offsets; init cursor = start ---
__global__ __launch_bounds__(1024) void scan_c_kernel(
    int* __restrict__ start, int* __restrict__ cursor,
    const int* __restrict__ offsets, int n) {
  const int i = blockIdx.x * 1024 + threadIdx.x;
  if (i < n) {
    const int v = start[i] + offsets[blockIdx.x];
    start[i] = v;
    cursor[i] = v;
  }
}

// --- Sort step 3: drop {col, a} into row segments (packed 8B) ---
__global__ __launch_bounds__(256) void permute_kernel(
    const int* __restrict__ rows, const int* __restrict__ cols,
    const float* __restrict__ a_vals, int* __restrict__ cursor,
    int2* __restrict__ meta, int E) {
  const int e = blockIdx.x * blockDim.x + threadIdx.x;
  if (e >= E) return;
  const int pos = atomicAdd(&cursor[rows[e]], 1);
  meta[pos] = make_int2(cols[e], __float_as_int(a_vals[e]));
}

// --- Phase 2: gather-reduce. One wave per row; lane owns 4 packed bf16 ch. ---
__global__ __launch_bounds__(256) void gather_kernel(
    const unsigned short* __restrict__ xwb, const int* __restrict__ start,
    const int2* __restrict__ meta, float* __restrict__ out,
    int N, int stride_b) {
  const int lane = threadIdx.x & 63;
  const int wid  = __builtin_amdgcn_readfirstlane(threadIdx.x >> 6);
  const int r = blockIdx.x * 4 + wid;
  if (r >= N) return;

  const int js = start[r];
  const int je = start[r + 1];
  const ushort4* __restrict__ xw4 = (const ushort4*)xwb;

  float ax = 0.f, ay = 0.f, az = 0.f, aw = 0.f;
  int j = js;
  for (; j + 2 <= je; j += 2) {
    const int2 m0 = meta[j];
    const int2 m1 = meta[j + 1];
    const ushort4 u0 = xw4[(size_t)m0.x * 64 + lane];
    const ushort4 u1 = xw4[(size_t)m1.x * 64 + lane];
    const float a0 = __int_as_float(m0.y);
    const float a1 = __int_as_float(m1.y);
    ax = fmaf(a0, bf2f(u0.x), ax);
    ay = fmaf(a0, bf2f(u0.y), ay);
    az = fmaf(a0, bf2f(u0.z), az);
    aw = fmaf(a0, bf2f(u0.w), aw);
    ax = fmaf(a1, bf2f(u1.x), ax);
    ay = fmaf(a1, bf2f(u1.y), ay);
    az = fmaf(a1, bf2f(u1.z), az);
    aw = fmaf(a1, bf2f(u1.w), aw);
  }
  if (j < je) {
    const int2 m0 = meta[j];
    const ushort4 u0 = xw4[(size_t)m0.x * 64 + lane];
    const float a0 = __int_as_float(m0.y);
    ax = fmaf(a0, bf2f(u0.x), ax);
    ay = fmaf(a0, bf2f(u0.y), ay);
    az = fmaf(a0, bf2f(u0.z), az);
    aw = fmaf(a0, bf2f(u0.w), aw);
  }

  const int i0 = lane * 4;       // packed idx in [0,256)
  const int b  = i0 >> 6;
  const int ch = i0 & 63;
  float4 o;
  o.x = ax; o.y = ay; o.z = az; o.w = aw;
  *(float4*)(out + (size_t)b * stride_b + (size_t)r * D + ch) = o;
}

extern "C" void kernel_launch(void* const* d_in, const int* in_sizes, int n_in,
                              void* d_out, int out_size, void* d_ws,
                              size_t ws_size, hipStream_t stream) {
  const float* x      = (const float*)d_in[0];
  const float* W      = (const float*)d_in[1];
  const int*   rows   = (const int*)d_in[2];
  const int*   cols   = (const int*)d_in[3];
  const float* a_vals = (const float*)d_in[4];

  const int E           = in_sizes[2];
  const int total_nodes = in_sizes[0] / D;  // B*N
  const int N           = total_nodes / BATCH;
  const int stride_b    = N * D;

  // Workspace layout (16B-aligned slabs)
  char* ws = (char*)d_ws;
  __hip_bfloat16* xwb = (__hip_bfloat16*)ws;  ws += (size_t)N * PACK * sizeof(__hip_bfloat16);
  int2* meta   = (int2*)ws;                   ws += (size_t)E * sizeof(int2);
  int* start   = (int*)ws;                    ws += (size_t)(N + 1) * sizeof(int);
  int* cursor  = (int*)ws;                    ws += (size_t)N * sizeof(int);
  int* partial = (int*)ws;                    ws += 64 * sizeof(int);
  int* offsets = (int*)ws;

  hipMemsetAsync(cursor, 0, (size_t)N * sizeof(int), stream);

  gemm_xw_kernel<<<2048, 256, 0, stream>>>(x, W, xwb, total_nodes, N);

  const int eb = (E + 255) / 256;
  hist_kernel<<<eb, 256, 0, stream>>>(rows, cursor, E);

  const int nb = (N + 1023) / 1024;
  scan_a_kernel<<<nb, 1024, 0, stream>>>(cursor, start, partial, N);
  scan_b_kernel<<<1, 64, 0, stream>>>(partial, offsets, start, nb, N, E);
  scan_c_kernel<<<nb, 1024, 0, stream>>>(start, cursor, offsets, N);

  permute_kernel<<<eb, 256, 0, stream>>>(rows, cols, a_vals, cursor, meta, E);

  const int gb = (N + 3) / 4;
  gather_kernel<<<gb, 256, 0, stream>>>((const unsigned short*)xwb, start, meta,
                                        (float*)d_out, N, stride_b);
}

// Round 4
// 284.828 us; speedup vs baseline: 10.6773x; 1.0973x over previous
//
#include <hip/hip_runtime.h>
#include <hip/hip_bf16.h>

#define D 64
#define BATCH 4
#define PACK 256  // packed floats per graph node: BATCH * D

__device__ __forceinline__ float bf2f(unsigned short h) {
  union { unsigned int u; float f; } v;
  v.u = ((unsigned int)h) << 16;
  return v.f;
}

// --- Phase 1 (fused): xwb[n][b*64+c] = bf16(sum_k x[b*N+n][k] * W[k][c])
//     + edge-degree histogram (grid-stride tail).
// Per block: 64 x-rows staged in LDS via linear coalesced float4 loads.
// W held in VGPRs (lane = channel c; W4[k4] = W[4k4..4k4+3][c]).
// Inner loop per node: 16 ds_read_b128 broadcasts + 64 FMA in 4 indep chains.
__global__ __launch_bounds__(256) void gemm_hist_kernel(
    const float* __restrict__ x, const float* __restrict__ W,
    __hip_bfloat16* __restrict__ xwb, const int* __restrict__ rows,
    int* __restrict__ cnt, int total_nodes, int N, int E) {
  __shared__ float4 xs[64 * 16];  // 64 rows x 16 float4 = 16 KB

  const int tid  = threadIdx.x;
  const int lane = tid & 63;
  const int wid  = __builtin_amdgcn_readfirstlane(tid >> 6);

  // W column 'lane' into registers (coalesced across lanes).
  float4 W4[16];
#pragma unroll
  for (int k4 = 0; k4 < 16; ++k4) {
    W4[k4].x = W[(4 * k4 + 0) * D + lane];
    W4[k4].y = W[(4 * k4 + 1) * D + lane];
    W4[k4].z = W[(4 * k4 + 2) * D + lane];
    W4[k4].w = W[(4 * k4 + 3) * D + lane];
  }

  const float4* __restrict__ x4 = (const float4*)x;
  const int ntiles = (total_nodes + 63) / 64;
  const size_t x4_total = (size_t)total_nodes * 16;

  for (int tile = blockIdx.x; tile < ntiles; tile += gridDim.x) {
    const int base = tile * 64;
    __syncthreads();
    // Linear coalesced staging: xs[i] = x4[base*16 + i]
    const size_t g0 = (size_t)base * 16;
#pragma unroll
    for (int i = 0; i < 4; ++i) {
      const int li = tid + i * 256;
      const size_t gi = g0 + li;
      xs[li] = (gi < x4_total) ? x4[gi]
                               : make_float4(0.f, 0.f, 0.f, 0.f);
    }
    __syncthreads();

#pragma unroll 2
    for (int m = 0; m < 16; ++m) {
      const int fn = base + wid * 16 + m;
      if (fn >= total_nodes) break;
      const int row = wid * 16 + m;
      float sx = 0.f, sy = 0.f, sz = 0.f, sw = 0.f;  // 4 indep chains
#pragma unroll
      for (int k4 = 0; k4 < 16; ++k4) {
        const float4 xv = xs[row * 16 + k4];  // LDS broadcast (free)
        sx = fmaf(xv.x, W4[k4].x, sx);
        sy = fmaf(xv.y, W4[k4].y, sy);
        sz = fmaf(xv.z, W4[k4].z, sz);
        sw = fmaf(xv.w, W4[k4].w, sw);
      }
      const float acc = (sx + sy) + (sz + sw);
      const int b = fn / N;
      const int n = fn - b * N;
      xwb[(size_t)n * PACK + b * D + lane] = __float2bfloat16(acc);
    }
  }

  // Fused degree histogram (independent of gemm data; cnt pre-zeroed by
  // the memset enqueued before this kernel).
  const int gtid = blockIdx.x * 256 + tid;
  const int gstr = gridDim.x * 256;
  for (int e = gtid; e < E; e += gstr) atomicAdd(&cnt[rows[e]], 1);
}

// --- Sort step 2a: per-block exclusive scan + block totals ---
__global__ __launch_bounds__(1024) void scan_a_kernel(
    const int* __restrict__ cnt, int* __restrict__ start,
    int* __restrict__ partial, int n) {
  __shared__ int s[1024];
  const int t = threadIdx.x;
  const int i = blockIdx.x * 1024 + t;
  const int v = (i < n) ? cnt[i] : 0;
  s[t] = v;
  __syncthreads();
  for (int off = 1; off < 1024; off <<= 1) {
    const int u = (t >= off) ? s[t - off] : 0;
    __syncthreads();
    s[t] += u;
    __syncthreads();
  }
  if (i < n) start[i] = s[t] - v;  // block-local exclusive
  if (t == 1023) partial[blockIdx.x] = s[1023];
}

// --- Sort step 2bc (fused): apply block offsets, init cursor, start[n]=E ---
__global__ __launch_bounds__(1024) void scan_bc_kernel(
    const int* __restrict__ partial, int* __restrict__ start,
    int* __restrict__ cursor, int n, int E) {
  __shared__ int soff;
  if (threadIdx.x < 64) {
    int v = 0;
    for (int j = threadIdx.x; j < (int)blockIdx.x; j += 64) v += partial[j];
#pragma unroll
    for (int d = 32; d > 0; d >>= 1) v += __shfl_down(v, d);
    if (threadIdx.x == 0) soff = v;
  }
  __syncthreads();
  const int i = blockIdx.x * 1024 + threadIdx.x;
  if (i < n) {
    const int sv = start[i] + soff;
    start[i] = sv;
    cursor[i] = sv;
  }
  if (blockIdx.x == 0 && threadIdx.x == 0) start[n] = E;
}

// --- Sort step 3: drop {col, a} into row segments (packed 8B) ---
__global__ __launch_bounds__(256) void permute_kernel(
    const int* __restrict__ rows, const int* __restrict__ cols,
    const float* __restrict__ a_vals, int* __restrict__ cursor,
    int2* __restrict__ meta, int E) {
  const int e = blockIdx.x * blockDim.x + threadIdx.x;
  if (e >= E) return;
  const int pos = atomicAdd(&cursor[rows[e]], 1);
  meta[pos] = make_int2(cols[e], __float_as_int(a_vals[e]));
}

// --- Phase 2: gather-reduce. One wave per row; lane owns 4 packed bf16 ch. ---
__global__ __launch_bounds__(256) void gather_kernel(
    const unsigned short* __restrict__ xwb, const int* __restrict__ start,
    const int2* __restrict__ meta, float* __restrict__ out,
    int N, int stride_b) {
  const int lane = threadIdx.x & 63;
  const int wid  = __builtin_amdgcn_readfirstlane(threadIdx.x >> 6);
  const int r = blockIdx.x * 4 + wid;
  if (r >= N) return;

  const int js = start[r];
  const int je = start[r + 1];
  const ushort4* __restrict__ xw4 = (const ushort4*)xwb;

  float ax = 0.f, ay = 0.f, az = 0.f, aw = 0.f;
  int j = js;
  for (; j + 2 <= je; j += 2) {
    const int2 m0 = meta[j];
    const int2 m1 = meta[j + 1];
    const ushort4 u0 = xw4[(size_t)m0.x * 64 + lane];
    const ushort4 u1 = xw4[(size_t)m1.x * 64 + lane];
    const float a0 = __int_as_float(m0.y);
    const float a1 = __int_as_float(m1.y);
    ax = fmaf(a0, bf2f(u0.x), ax);
    ay = fmaf(a0, bf2f(u0.y), ay);
    az = fmaf(a0, bf2f(u0.z), az);
    aw = fmaf(a0, bf2f(u0.w), aw);
    ax = fmaf(a1, bf2f(u1.x), ax);
    ay = fmaf(a1, bf2f(u1.y), ay);
    az = fmaf(a1, bf2f(u1.z), az);
    aw = fmaf(a1, bf2f(u1.w), aw);
  }
  if (j < je) {
    const int2 m0 = meta[j];
    const ushort4 u0 = xw4[(size_t)m0.x * 64 + lane];
    const float a0 = __int_as_float(m0.y);
    ax = fmaf(a0, bf2f(u0.x), ax);
    ay = fmaf(a0, bf2f(u0.y), ay);
    az = fmaf(a0, bf2f(u0.z), az);
    aw = fmaf(a0, bf2f(u0.w), aw);
  }

  const int i0 = lane * 4;  // packed idx in [0,256)
  const int b  = i0 >> 6;
  const int ch = i0 & 63;
  float4 o;
  o.x = ax; o.y = ay; o.z = az; o.w = aw;
  *(float4*)(out + (size_t)b * stride_b + (size_t)r * D + ch) = o;
}

extern "C" void kernel_launch(void* const* d_in, const int* in_sizes, int n_in,
                              void* d_out, int out_size, void* d_ws,
                              size_t ws_size, hipStream_t stream) {
  const float* x      = (const float*)d_in[0];
  const float* W      = (const float*)d_in[1];
  const int*   rows   = (const int*)d_in[2];
  const int*   cols   = (const int*)d_in[3];
  const float* a_vals = (const float*)d_in[4];

  const int E           = in_sizes[2];
  const int total_nodes = in_sizes[0] / D;  // B*N
  const int N           = total_nodes / BATCH;
  const int stride_b    = N * D;

  // Workspace layout (16B-aligned slabs)
  char* ws = (char*)d_ws;
  __hip_bfloat16* xwb = (__hip_bfloat16*)ws;  ws += (size_t)N * PACK * sizeof(__hip_bfloat16);
  int2* meta   = (int2*)ws;                   ws += (size_t)E * sizeof(int2);
  int* start   = (int*)ws;                    ws += (size_t)(N + 1) * sizeof(int);
  int* cursor  = (int*)ws;                    ws += (size_t)N * sizeof(int);
  int* partial = (int*)ws;

  hipMemsetAsync(cursor, 0, (size_t)N * sizeof(int), stream);

  gemm_hist_kernel<<<1024, 256, 0, stream>>>(x, W, xwb, rows, cursor,
                                             total_nodes, N, E);

  const int nb = (N + 1023) / 1024;
  scan_a_kernel<<<nb, 1024, 0, stream>>>(cursor, start, partial, N);
  scan_bc_kernel<<<nb, 1024, 0, stream>>>(partial, start, cursor, N, E);

  const int eb = (E + 255) / 256;
  permute_kernel<<<eb, 256, 0, stream>>>(rows, cols, a_vals, cursor, meta, E);

  const int gb = (N + 3) / 4;
  gather_kernel<<<gb, 256, 0, stream>>>((const unsigned short*)xwb, start, meta,
                                        (float*)d_out, N, stride_b);
}

// Round 5
// 274.469 us; speedup vs baseline: 11.0803x; 1.0377x over previous
//
#include <hip/hip_runtime.h>

#define D 64
#define PACK 256   // packed floats per node: BATCH * D
#define BSHIFT 11  // col bucket = col >> 11 (2048 nodes = 1 MB bf16 per bucket)

typedef __attribute__((ext_vector_type(8))) short bf16x8;
typedef __attribute__((ext_vector_type(4))) float f32x4;

__device__ __forceinline__ unsigned short f2bf(float f) {
  unsigned int u = __float_as_uint(f);
  u += 0x7FFFu + ((u >> 16) & 1u);  // RNE (inputs finite)
  return (unsigned short)(u >> 16);
}
__device__ __forceinline__ float bf2f(unsigned short h) {
  union { unsigned int u; float f; } v;
  v.u = ((unsigned int)h) << 16;
  return v.f;
}

// --- Phase 1 (fused): xwb = bf16(x @ W) via MFMA + (row,colbucket) histogram.
// Wave = 16-node M-tile, full N=64. A-frags from global (2 float4/lane),
// B(W) in 32 VGPRs. 8 mfma_f32_16x16x32_bf16 per tile. No LDS.
__global__ __launch_bounds__(256) void gemm_hist_kernel(
    const float* __restrict__ x, const float* __restrict__ W,
    unsigned short* __restrict__ xwb, const int* __restrict__ rows,
    const int* __restrict__ cols, int* __restrict__ bins,
    int total_nodes, int N, int E, int NB) {
  const int tid  = threadIdx.x;
  const int lane = tid & 63;
  const int c = lane & 15;  // m (A) / n (B) / col (D) within 16-tile
  const int q = lane >> 4;  // quad: k-octet (A,B) / row-group (D)

  // B-operand frags: B[k][n] = W[k*64+n]; n = nt*16+c, k = h*32 + q*8 + j.
  bf16x8 Bf[4][2];
#pragma unroll
  for (int nt = 0; nt < 4; ++nt) {
#pragma unroll
    for (int h = 0; h < 2; ++h) {
      const int n  = nt * 16 + c;
      const int k0 = h * 32 + q * 8;
#pragma unroll
      for (int j = 0; j < 8; ++j)
        Bf[nt][h][j] = (short)f2bf(W[(k0 + j) * D + n]);
    }
  }

  const float4* __restrict__ x4 = (const float4*)x;
  const int ntiles = (total_nodes + 15) >> 4;
  const int wave_g = blockIdx.x * 4 + (tid >> 6);
  const int nwaves = gridDim.x * 4;

  for (int tile = wave_g; tile < ntiles; tile += nwaves) {
    const int base = tile * 16;
    const int node = min(base + c, total_nodes - 1);
    const float4* xr = x4 + (size_t)node * 16;
    // A[m=c][k=q*8+j] (+32 for second frag): 8 consecutive floats per frag.
    const float4 p0 = xr[q * 2 + 0];
    const float4 p1 = xr[q * 2 + 1];
    const float4 p2 = xr[8 + q * 2 + 0];
    const float4 p3 = xr[8 + q * 2 + 1];
    bf16x8 a0, a1;
    a0[0] = (short)f2bf(p0.x); a0[1] = (short)f2bf(p0.y);
    a0[2] = (short)f2bf(p0.z); a0[3] = (short)f2bf(p0.w);
    a0[4] = (short)f2bf(p1.x); a0[5] = (short)f2bf(p1.y);
    a0[6] = (short)f2bf(p1.z); a0[7] = (short)f2bf(p1.w);
    a1[0] = (short)f2bf(p2.x); a1[1] = (short)f2bf(p2.y);
    a1[2] = (short)f2bf(p2.z); a1[3] = (short)f2bf(p2.w);
    a1[4] = (short)f2bf(p3.x); a1[5] = (short)f2bf(p3.y);
    a1[6] = (short)f2bf(p3.z); a1[7] = (short)f2bf(p3.w);

    f32x4 acc[4];
#pragma unroll
    for (int nt = 0; nt < 4; ++nt) {
      f32x4 z = {0.f, 0.f, 0.f, 0.f};
      z = __builtin_amdgcn_mfma_f32_16x16x32_bf16(a0, Bf[nt][0], z, 0, 0, 0);
      z = __builtin_amdgcn_mfma_f32_16x16x32_bf16(a1, Bf[nt][1], z, 0, 0, 0);
      acc[nt] = z;
    }
    // D: node m = q*4 + r, ch = nt*16 + c.
#pragma unroll
    for (int r = 0; r < 4; ++r) {
      const int fn = base + q * 4 + r;
      if (fn >= total_nodes) break;
      const int b  = (fn >= N) + (fn >= 2 * N) + (fn >= 3 * N);
      const int nn = fn - b * N;
      unsigned short* dst = xwb + (size_t)nn * PACK + b * D + c;
#pragma unroll
      for (int nt = 0; nt < 4; ++nt) dst[nt * 16] = f2bf(acc[nt][r]);
    }
  }

  // Fused (row, colbucket) histogram; bins pre-zeroed by the memset.
  const int gtid = blockIdx.x * 256 + tid;
  const int gstr = gridDim.x * 256;
  for (int e = gtid; e < E; e += gstr) {
    const int bkt = ((unsigned)cols[e]) >> BSHIFT;
    atomicAdd(&bins[rows[e] * NB + bkt], 1);
  }
}

// --- Sort step 2a: per-block exclusive scan + block totals ---
__global__ __launch_bounds__(1024) void scan_a_kernel(
    const int* __restrict__ cnt, int* __restrict__ start,
    int* __restrict__ partial, int n) {
  __shared__ int s[1024];
  const int t = threadIdx.x;
  const int i = blockIdx.x * 1024 + t;
  const int v = (i < n) ? cnt[i] : 0;
  s[t] = v;
  __syncthreads();
  for (int off = 1; off < 1024; off <<= 1) {
    const int u = (t >= off) ? s[t - off] : 0;
    __syncthreads();
    s[t] += u;
    __syncthreads();
  }
  if (i < n) start[i] = s[t] - v;
  if (t == 1023) partial[blockIdx.x] = s[1023];
}

// --- Sort step 2bc: apply block offsets, init cursor, start[n]=E ---
__global__ __launch_bounds__(1024) void scan_bc_kernel(
    const int* __restrict__ partial, int* __restrict__ start,
    int* __restrict__ cursor, int n, int E) {
  __shared__ int soff;
  if (threadIdx.x < 64) {
    int v = 0;
    for (int j = threadIdx.x; j < (int)blockIdx.x; j += 64) v += partial[j];
#pragma unroll
    for (int d = 32; d > 0; d >>= 1) v += __shfl_down(v, d);
    if (threadIdx.x == 0) soff = v;
  }
  __syncthreads();
  const int i = blockIdx.x * 1024 + threadIdx.x;
  if (i < n) {
    const int sv = start[i] + soff;
    start[i] = sv;
    cursor[i] = sv;
  }
  if (blockIdx.x == 0 && threadIdx.x == 0) start[n] = E;
}

// --- Sort step 3: drop {col,a} into (row,bucket) segments ---
__global__ __launch_bounds__(256) void permute_kernel(
    const int* __restrict__ rows, const int* __restrict__ cols,
    const float* __restrict__ a_vals, int* __restrict__ cursor,
    int2* __restrict__ meta, int E, int NB) {
  const int e = blockIdx.x * blockDim.x + threadIdx.x;
  if (e >= E) return;
  const int col = cols[e];
  const int bkt = ((unsigned)col) >> BSHIFT;
  const int pos = atomicAdd(&cursor[rows[e] * NB + bkt], 1);
  meta[pos] = make_int2(col, __float_as_int(a_vals[e]));
}

// --- Phase 2: gather-reduce. One wave per row; edges bucket-ordered. ---
__global__ __launch_bounds__(256) void gather_kernel(
    const unsigned short* __restrict__ xwb, const int* __restrict__ start,
    const int2* __restrict__ meta, float* __restrict__ out,
    int N, int stride_b, int NB) {
  const int lane = threadIdx.x & 63;
  const int wid  = __builtin_amdgcn_readfirstlane(threadIdx.x >> 6);
  const int r = blockIdx.x * 4 + wid;
  if (r >= N) return;

  const int js = start[(size_t)r * NB];
  const int je = start[(size_t)(r + 1) * NB];
  const ushort4* __restrict__ xw4 = (const ushort4*)xwb;

  float ax = 0.f, ay = 0.f, az = 0.f, aw = 0.f;
  int j = js;
  for (; j + 4 <= je; j += 4) {
    const int2 m0 = meta[j], m1 = meta[j + 1], m2 = meta[j + 2],
               m3 = meta[j + 3];
    const ushort4 u0 = xw4[(size_t)m0.x * 64 + lane];
    const ushort4 u1 = xw4[(size_t)m1.x * 64 + lane];
    const ushort4 u2 = xw4[(size_t)m2.x * 64 + lane];
    const ushort4 u3 = xw4[(size_t)m3.x * 64 + lane];
    const float a0 = __int_as_float(m0.y), a1 = __int_as_float(m1.y);
    const float a2 = __int_as_float(m2.y), a3 = __int_as_float(m3.y);
    ax = fmaf(a0, bf2f(u0.x), ax); ay = fmaf(a0, bf2f(u0.y), ay);
    az = fmaf(a0, bf2f(u0.z), az); aw = fmaf(a0, bf2f(u0.w), aw);
    ax = fmaf(a1, bf2f(u1.x), ax); ay = fmaf(a1, bf2f(u1.y), ay);
    az = fmaf(a1, bf2f(u1.z), az); aw = fmaf(a1, bf2f(u1.w), aw);
    ax = fmaf(a2, bf2f(u2.x), ax); ay = fmaf(a2, bf2f(u2.y), ay);
    az = fmaf(a2, bf2f(u2.z), az); aw = fmaf(a2, bf2f(u2.w), aw);
    ax = fmaf(a3, bf2f(u3.x), ax); ay = fmaf(a3, bf2f(u3.y), ay);
    az = fmaf(a3, bf2f(u3.z), az); aw = fmaf(a3, bf2f(u3.w), aw);
  }
  for (; j < je; ++j) {
    const int2 m0 = meta[j];
    const ushort4 u0 = xw4[(size_t)m0.x * 64 + lane];
    const float a0 = __int_as_float(m0.y);
    ax = fmaf(a0, bf2f(u0.x), ax); ay = fmaf(a0, bf2f(u0.y), ay);
    az = fmaf(a0, bf2f(u0.z), az); aw = fmaf(a0, bf2f(u0.w), aw);
  }

  const int i0 = lane * 4;  // packed idx in [0,256)
  const int b  = i0 >> 6;
  const int ch = i0 & 63;
  float4 o;
  o.x = ax; o.y = ay; o.z = az; o.w = aw;
  *(float4*)(out + (size_t)b * stride_b + (size_t)r * D + ch) = o;
}

extern "C" void kernel_launch(void* const* d_in, const int* in_sizes, int n_in,
                              void* d_out, int out_size, void* d_ws,
                              size_t ws_size, hipStream_t stream) {
  const float* x      = (const float*)d_in[0];
  const float* W      = (const float*)d_in[1];
  const int*   rows   = (const int*)d_in[2];
  const int*   cols   = (const int*)d_in[3];
  const float* a_vals = (const float*)d_in[4];

  const int E           = in_sizes[2];
  const int total_nodes = in_sizes[0] / D;  // B*N
  const int N           = total_nodes / 4;
  const int stride_b    = N * D;
  const int NB          = (N + (1 << BSHIFT) - 1) >> BSHIFT;
  const int nbins       = N * NB;

  // Workspace layout (16B-aligned slabs)
  char* ws = (char*)d_ws;
  unsigned short* xwb = (unsigned short*)ws;  ws += (size_t)N * PACK * sizeof(unsigned short);
  int2* meta   = (int2*)ws;                   ws += (size_t)E * sizeof(int2);
  int* start   = (int*)ws;                    ws += (size_t)(nbins + 4) * sizeof(int);
  int* cursor  = (int*)ws;                    ws += (size_t)nbins * sizeof(int);
  int* partial = (int*)ws;

  hipMemsetAsync(cursor, 0, (size_t)nbins * sizeof(int), stream);

  gemm_hist_kernel<<<512, 256, 0, stream>>>(x, W, xwb, rows, cols, cursor,
                                            total_nodes, N, E, NB);

  const int sb = (nbins + 1023) / 1024;
  scan_a_kernel<<<sb, 1024, 0, stream>>>(cursor, start, partial, nbins);
  scan_bc_kernel<<<sb, 1024, 0, stream>>>(partial, start, cursor, nbins, E);

  const int eb = (E + 255) / 256;
  permute_kernel<<<eb, 256, 0, stream>>>(rows, cols, a_vals, cursor, meta, E, NB);

  const int gb = (N + 3) / 4;
  gather_kernel<<<gb, 256, 0, stream>>>(xwb, start, meta, (float*)d_out, N,
                                        stride_b, NB);
}

// Round 6
// 251.439 us; speedup vs baseline: 12.0951x; 1.0916x over previous
//
#include <hip/hip_runtime.h>

#define D 64
#define PACK 256  // packed floats per node: BATCH * D

typedef __attribute__((ext_vector_type(8))) short bf16x8;
typedef __attribute__((ext_vector_type(4))) float f32x4;

__device__ __forceinline__ unsigned short f2bf(float f) {
  unsigned int u = __float_as_uint(f);
  u += 0x7FFFu + ((u >> 16) & 1u);  // RNE (inputs finite)
  return (unsigned short)(u >> 16);
}
__device__ __forceinline__ float bf2f(unsigned short h) {
  union { unsigned int u; float f; } v;
  v.u = ((unsigned int)h) << 16;
  return v.f;
}

// --- Phase 1 (fused): xwb = bf16(x @ W) via MFMA + row-degree histogram.
// Wave = 16-node M-tile, full N=64. A-frags from global (4 float4/lane),
// B(W) in 32 VGPRs. 8 mfma_f32_16x16x32_bf16 per tile. No LDS.
__global__ __launch_bounds__(256) void gemm_hist_kernel(
    const float* __restrict__ x, const float* __restrict__ W,
    unsigned short* __restrict__ xwb, const int* __restrict__ rows,
    int* __restrict__ cnt, int total_nodes, int N, int E) {
  const int tid  = threadIdx.x;
  const int lane = tid & 63;
  const int c = lane & 15;  // m (A) / n (B) / col (D) within 16-tile
  const int q = lane >> 4;  // quad: k-octet (A,B) / row-group (D)

  // B-operand frags: B[k][n] = W[k*64+n]; n = nt*16+c, k = h*32 + q*8 + j.
  bf16x8 Bf[4][2];
#pragma unroll
  for (int nt = 0; nt < 4; ++nt) {
#pragma unroll
    for (int h = 0; h < 2; ++h) {
      const int n  = nt * 16 + c;
      const int k0 = h * 32 + q * 8;
#pragma unroll
      for (int j = 0; j < 8; ++j)
        Bf[nt][h][j] = (short)f2bf(W[(k0 + j) * D + n]);
    }
  }

  const float4* __restrict__ x4 = (const float4*)x;
  const int ntiles = (total_nodes + 15) >> 4;
  const int wave_g = blockIdx.x * 4 + (tid >> 6);
  const int nwaves = gridDim.x * 4;

  for (int tile = wave_g; tile < ntiles; tile += nwaves) {
    const int base = tile * 16;
    const int node = min(base + c, total_nodes - 1);
    const float4* xr = x4 + (size_t)node * 16;
    const float4 p0 = xr[q * 2 + 0];
    const float4 p1 = xr[q * 2 + 1];
    const float4 p2 = xr[8 + q * 2 + 0];
    const float4 p3 = xr[8 + q * 2 + 1];
    bf16x8 a0, a1;
    a0[0] = (short)f2bf(p0.x); a0[1] = (short)f2bf(p0.y);
    a0[2] = (short)f2bf(p0.z); a0[3] = (short)f2bf(p0.w);
    a0[4] = (short)f2bf(p1.x); a0[5] = (short)f2bf(p1.y);
    a0[6] = (short)f2bf(p1.z); a0[7] = (short)f2bf(p1.w);
    a1[0] = (short)f2bf(p2.x); a1[1] = (short)f2bf(p2.y);
    a1[2] = (short)f2bf(p2.z); a1[3] = (short)f2bf(p2.w);
    a1[4] = (short)f2bf(p3.x); a1[5] = (short)f2bf(p3.y);
    a1[6] = (short)f2bf(p3.z); a1[7] = (short)f2bf(p3.w);

    f32x4 acc[4];
#pragma unroll
    for (int nt = 0; nt < 4; ++nt) {
      f32x4 z = {0.f, 0.f, 0.f, 0.f};
      z = __builtin_amdgcn_mfma_f32_16x16x32_bf16(a0, Bf[nt][0], z, 0, 0, 0);
      z = __builtin_amdgcn_mfma_f32_16x16x32_bf16(a1, Bf[nt][1], z, 0, 0, 0);
      acc[nt] = z;
    }
    // D: node m = q*4 + r, ch = nt*16 + c.
#pragma unroll
    for (int r = 0; r < 4; ++r) {
      const int fn = base + q * 4 + r;
      if (fn >= total_nodes) break;
      const int b  = (fn >= N) + (fn >= 2 * N) + (fn >= 3 * N);
      const int nn = fn - b * N;
      unsigned short* dst = xwb + (size_t)nn * PACK + b * D + c;
#pragma unroll
      for (int nt = 0; nt < 4; ++nt) dst[nt * 16] = f2bf(acc[nt][r]);
    }
  }

  // Fused row-degree histogram; cnt pre-zeroed by the memset.
  const int gtid = blockIdx.x * 256 + tid;
  const int gstr = gridDim.x * 256;
  for (int e = gtid; e < E; e += gstr) atomicAdd(&cnt[rows[e]], 1);
}

// --- Sort step 2a: per-block exclusive scan + block totals ---
__global__ __launch_bounds__(1024) void scan_a_kernel(
    const int* __restrict__ cnt, int* __restrict__ start,
    int* __restrict__ partial, int n) {
  __shared__ int s[1024];
  const int t = threadIdx.x;
  const int i = blockIdx.x * 1024 + t;
  const int v = (i < n) ? cnt[i] : 0;
  s[t] = v;
  __syncthreads();
  for (int off = 1; off < 1024; off <<= 1) {
    const int u = (t >= off) ? s[t - off] : 0;
    __syncthreads();
    s[t] += u;
    __syncthreads();
  }
  if (i < n) start[i] = s[t] - v;
  if (t == 1023) partial[blockIdx.x] = s[1023];
}

// --- Sort step 2bc: apply block offsets, init cursor, start[n]=E ---
__global__ __launch_bounds__(1024) void scan_bc_kernel(
    const int* __restrict__ partial, int* __restrict__ start,
    int* __restrict__ cursor, int n, int E) {
  __shared__ int soff;
  if (threadIdx.x < 64) {
    int v = 0;
    for (int j = threadIdx.x; j < (int)blockIdx.x; j += 64) v += partial[j];
#pragma unroll
    for (int d = 32; d > 0; d >>= 1) v += __shfl_down(v, d);
    if (threadIdx.x == 0) soff = v;
  }
  __syncthreads();
  const int i = blockIdx.x * 1024 + threadIdx.x;
  if (i < n) {
    const int sv = start[i] + soff;
    start[i] = sv;
    cursor[i] = sv;
  }
  if (blockIdx.x == 0 && threadIdx.x == 0) start[n] = E;
}

// --- Sort step 3: drop {col,a} into row segments ---
__global__ __launch_bounds__(256) void permute_kernel(
    const int* __restrict__ rows, const int* __restrict__ cols,
    const float* __restrict__ a_vals, int* __restrict__ cursor,
    int2* __restrict__ meta, int E) {
  const int e = blockIdx.x * blockDim.x + threadIdx.x;
  if (e >= E) return;
  const int pos = atomicAdd(&cursor[rows[e]], 1);
  meta[pos] = make_int2(cols[e], __float_as_int(a_vals[e]));
}

// --- Phase 2: gather-reduce. One wave per row. Meta loaded 64-edges-at-a-
// time coalesced (lane l -> edge j0+l), broadcast via readlane; 8 gathers
// issued back-to-back per group for deep MLP. ---
__global__ __launch_bounds__(256) void gather_kernel(
    const unsigned short* __restrict__ xwb, const int* __restrict__ start,
    const int2* __restrict__ meta, float* __restrict__ out,
    int N, int stride_b) {
  const int lane = threadIdx.x & 63;
  const int r = blockIdx.x * 4 + (threadIdx.x >> 6);
  if (r >= N) return;

  int j0 = start[r];
  const int je = start[r + 1];
  const ushort4* __restrict__ xw4 = (const ushort4*)xwb;

  float ax = 0.f, ay = 0.f, az = 0.f, aw = 0.f;
  while (j0 < je) {
    const int cnt = min(64, je - j0);
    const int2 mv = meta[j0 + min(lane, cnt - 1)];  // coalesced 8B/lane
#pragma unroll
    for (int k = 0; k < 64; k += 8) {
      if (k >= cnt) break;
      int   cc[8];
      float aa[8];
      ushort4 uu[8];
#pragma unroll
      for (int i = 0; i < 8; ++i) {
        cc[i] = __builtin_amdgcn_readlane(mv.x, k + i);
        aa[i] = (k + i < cnt)
                    ? __int_as_float(__builtin_amdgcn_readlane(mv.y, k + i))
                    : 0.f;  // padded edges: valid (clamped) col, zero weight
      }
#pragma unroll
      for (int i = 0; i < 8; ++i)
        uu[i] = xw4[(size_t)cc[i] * 64 + lane];  // 8 independent gathers
#pragma unroll
      for (int i = 0; i < 8; ++i) {
        ax = fmaf(aa[i], bf2f(uu[i].x), ax);
        ay = fmaf(aa[i], bf2f(uu[i].y), ay);
        az = fmaf(aa[i], bf2f(uu[i].z), az);
        aw = fmaf(aa[i], bf2f(uu[i].w), aw);
      }
    }
    j0 += 64;
  }

  const int i0 = lane * 4;  // packed idx in [0,256)
  const int b  = i0 >> 6;
  const int ch = i0 & 63;
  float4 o;
  o.x = ax; o.y = ay; o.z = az; o.w = aw;
  *(float4*)(out + (size_t)b * stride_b + (size_t)r * D + ch) = o;
}

extern "C" void kernel_launch(void* const* d_in, const int* in_sizes, int n_in,
                              void* d_out, int out_size, void* d_ws,
                              size_t ws_size, hipStream_t stream) {
  const float* x      = (const float*)d_in[0];
  const float* W      = (const float*)d_in[1];
  const int*   rows   = (const int*)d_in[2];
  const int*   cols   = (const int*)d_in[3];
  const float* a_vals = (const float*)d_in[4];

  const int E           = in_sizes[2];
  const int total_nodes = in_sizes[0] / D;  // B*N
  const int N           = total_nodes / 4;
  const int stride_b    = N * D;

  // Workspace layout (16B-aligned slabs)
  char* ws = (char*)d_ws;
  unsigned short* xwb = (unsigned short*)ws;  ws += (size_t)N * PACK * sizeof(unsigned short);
  int2* meta   = (int2*)ws;                   ws += (size_t)E * sizeof(int2);
  int* start   = (int*)ws;                    ws += (size_t)(N + 4) * sizeof(int);
  int* cursor  = (int*)ws;                    ws += (size_t)N * sizeof(int);
  int* partial = (int*)ws;

  hipMemsetAsync(cursor, 0, (size_t)N * sizeof(int), stream);

  gemm_hist_kernel<<<2048, 256, 0, stream>>>(x, W, xwb, rows, cursor,
                                             total_nodes, N, E);

  const int sb = (N + 1023) / 1024;
  scan_a_kernel<<<sb, 1024, 0, stream>>>(cursor, start, partial, N);
  scan_bc_kernel<<<sb, 1024, 0, stream>>>(partial, start, cursor, N, E);

  const int eb = (E + 255) / 256;
  permute_kernel<<<eb, 256, 0, stream>>>(rows, cols, a_vals, cursor, meta, E);

  const int gb = (N + 3) / 4;
  gather_kernel<<<gb, 256, 0, stream>>>(xwb, start, meta, (float*)d_out, N,
                                        stride_b);
}